// Round 13
// baseline (563.492 us; speedup 1.0000x reference)
//
#include <hip/hip_runtime.h>
#include <math.h>

#define NN 50
#define DD 128
#define NITS 64            // b's per block (grid = B/NITS = 512)
#define BMAX 32768

typedef __attribute__((ext_vector_type(4))) float  f32x4;
typedef __attribute__((ext_vector_type(2))) __fp16 f16x2;
typedef __attribute__((ext_vector_type(8))) __fp16 f16x8;

__device__ float g_WA1f[DD * DD];
__device__ float g_WA2f[DD * DD];
// swizzled fp16 weight table [col 0..255][k], byte-addr ^= ((col&7)<<4) baked in
__device__ __attribute__((aligned(16))) __fp16 g_WtS[2 * DD * DD];
__device__ __fp16 g_pxa[BMAX * DD];   // pxa[b][d] = A_b[d] + (x[b] @ W @ A1)[d]

__global__ void compute_WA(const float* __restrict__ W,
                           const float* __restrict__ A_w) {
    const int d = threadIdx.x, k = blockIdx.x, m = blockIdx.y;
    const float* __restrict__ A = A_w + (size_t)m * DD * DD;
    float acc = 0.f;
#pragma unroll 8
    for (int j = 0; j < DD; ++j)
        acc = fmaf(W[k * DD + j], A[j * DD + d], acc);
    if (m == 0) g_WA1f[k * DD + d] = acc;
    else        g_WA2f[k * DD + d] = acc;
}

// fp16 [W | W@A2]^T with the LDS bank-XOR baked into the element index.
__global__ void cvt_weights(const float* __restrict__ W) {
    const int n = blockIdx.x;      // col 0..255
    const int k = threadIdx.x;     // 0..127
    const float v = (n < DD) ? W[k * DD + n] : g_WA2f[k * DD + (n - DD)];
    const int idx = (n * DD + k) ^ ((n & 7) << 3);   // u16 idx; byte ^ ((n&7)<<4)
    g_WtS[idx] = (__fp16)v;
}

// pxa precompute: block = 128 thr, 32 b's; k-outer keeps WA1f read once/block.
__global__ __launch_bounds__(128, 8)
void pxa_pre(const float* __restrict__ x, const float* __restrict__ A_b, int B) {
    const int d  = threadIdx.x;
    const int b0 = blockIdx.x * 32;
    float acc[32];
    const float ab = A_b[d];
#pragma unroll
    for (int i = 0; i < 32; ++i) acc[i] = ab;
#pragma unroll 4
    for (int k = 0; k < DD; ++k) {
        const float wv = g_WA1f[k * DD + d];
#pragma unroll
        for (int i = 0; i < 32; ++i)
            acc[i] = fmaf(x[(size_t)(b0 + i) * DD + k], wv, acc[i]);
    }
#pragma unroll
    for (int i = 0; i < 32; ++i)
        g_pxa[(size_t)(b0 + i) * DD + d] = (__fp16)acc[i];
}

__device__ __forceinline__ f16x8 cvt8(float4 f0, float4 f1) {
    union { f16x2 h[4]; f16x8 v; } u;
    u.h[0] = __builtin_amdgcn_cvt_pkrtz(f0.x, f0.y);
    u.h[1] = __builtin_amdgcn_cvt_pkrtz(f0.z, f0.w);
    u.h[2] = __builtin_amdgcn_cvt_pkrtz(f1.x, f1.y);
    u.h[3] = __builtin_amdgcn_cvt_pkrtz(f1.z, f1.w);
    return u.v;
}

#define MFMA(a, b, c) __builtin_amdgcn_mfma_f32_16x16x32_f16((a), (b), (c), 0, 0, 0)

// v13: barrier-decoupled dataflow. 8 waves co-own each b: (h = row-half,
// q = col-quarter). A-fragments load DIRECTLY global->reg (no LDS tile, no
// ds_writes in loop; twin reads are same-CU L1/L2 hits — r12 showed cross-
// block sharing goes cross-XCD -> HBM). Weights live in LDS read-only.
// Softmax needs only SUMS (no max-shift) -> 2KB exchange + ONE barrier per b
// with lgkmcnt only: the A-prefetch stream is never drained (r6-r10 all
// gated HBM on a per-tile vmcnt/barrier). ~105 VGPR -> 4 waves/SIMD.
__global__ __launch_bounds__(512, 4)
void attn_mfma(const float* __restrict__ nbr, float* __restrict__ out, int B) {
    __shared__ __attribute__((aligned(16))) __fp16 wlds[2 * DD * DD]; // 64 KB
    __shared__ float exch[2][4][2][32];                               // 2 KB

    const int tid  = threadIdx.x;
    const int w    = tid >> 6;
    const int lane = tid & 63;
    const int c    = lane & 15;
    const int g    = lane >> 4;
    const int h    = w >> 2;        // row-half: rows 32h..32h+31
    const int q    = w & 3;         // col-quarter: cols 32q..32q+31
    const int b0   = blockIdx.x * NITS;

    // ---- prologue: weights -> LDS (linear copy; swizzle baked in table) ----
#pragma unroll
    for (int j = 0; j < 8; ++j) {
        const int off = j * 8192 + tid * 16;
        __builtin_amdgcn_global_load_lds(
            (const __attribute__((address_space(1))) void*)((const char*)g_WtS + off),
            (__attribute__((address_space(3))) void*)((char*)wlds + off), 16, 0, 0);
    }
    __syncthreads();   // one-time full drain; loop barriers never drain vmcnt

    // A-row float4-indices (fixed per wave): rows 32h+c, 32h+16+c (clamped)
    const int r0 = (32 * h + c      > NN - 1 ? NN - 1 : 32 * h + c)      * 32 + 2 * g;
    const int r1 = (32 * h + 16 + c > NN - 1 ? NN - 1 : 32 * h + 16 + c) * 32 + 2 * g;
    // LDS B-frag per-lane addr per kt (XOR swizzle folded)
    int vk[4];
#pragma unroll
    for (int kt = 0; kt < 4; ++kt)
        vk[kt] = c * 256 + ((kt * 64 + g * 16) ^ ((c & 7) << 4));
    const char* wb = (const char*)wlds;

    // masks for pad rows (only h==1, lm==1 tile: rows 48..63, valid n<50)
    const float mk01 = h ? ((g == 0) ? 1.f : 0.f) : 1.f;  // r=0,1 slots
    const float mk23 = h ? 0.f : 1.f;                     // r=2,3 slots

    float4 BUFA[4], BUFB[4];
#define LOADK(BUF, nb4, kt) do {                                         \
        BUF[0] = nb4[r0 + (kt) * 8];  BUF[1] = nb4[r0 + (kt) * 8 + 1];   \
        BUF[2] = nb4[r1 + (kt) * 8];  BUF[3] = nb4[r1 + (kt) * 8 + 1];   \
    } while (0)

    f32x4 acc[2][2][2];   // [lm][p][nt]

#define PHASE(BUF, KTC, NB4, KTL) do {                                   \
        const f16x8 A0 = cvt8(BUF[0], BUF[1]);                           \
        const f16x8 A1 = cvt8(BUF[2], BUF[3]);                           \
        LOADK(BUF, NB4, KTL);                                            \
        __builtin_amdgcn_sched_barrier(0);                               \
        _Pragma("unroll") for (int p = 0; p < 2; ++p)                    \
        _Pragma("unroll") for (int nt = 0; nt < 2; ++nt) {               \
            const f16x8 Bf = *(const f16x8*)(wb + vk[KTC] +              \
                (p * 32768 + q * 8192 + nt * 4096));                     \
            acc[0][p][nt] = MFMA(A0, Bf, acc[0][p][nt]);                 \
            acc[1][p][nt] = MFMA(A1, Bf, acc[1][p][nt]);                 \
        }                                                                \
    } while (0)

    {   // stream prologue: b0's kt0, kt1
        const float4* nb4 = (const float4*)(nbr + (size_t)b0 * (NN * DD));
        LOADK(BUFA, nb4, 0);
        LOADK(BUFB, nb4, 1);
        __builtin_amdgcn_sched_barrier(0);
    }

#pragma unroll 1
    for (int i = 0; i < NITS; ++i) {
        const int b  = b0 + i;
        const int bn = (i < NITS - 1) ? b + 1 : b;
        const float4* nb4c = (const float4*)(nbr + (size_t)b  * (NN * DD));
        const float4* nb4n = (const float4*)(nbr + (size_t)bn * (NN * DD));
        const float pxv0 = (float)g_pxa[(size_t)b * DD + q * 32 + c];
        const float pxv1 = (float)g_pxa[(size_t)b * DD + q * 32 + 16 + c];

#pragma unroll
        for (int lm = 0; lm < 2; ++lm)
#pragma unroll
            for (int p = 0; p < 2; ++p)
#pragma unroll
                for (int nt = 0; nt < 2; ++nt) acc[lm][p][nt] = (f32x4)0.f;

        PHASE(BUFA, 0, nb4c, 2);
        PHASE(BUFB, 1, nb4c, 3);
        PHASE(BUFA, 2, nb4n, 0);
        PHASE(BUFB, 3, nb4n, 1);

        // partial softmax over this wave's 32 rows (plain sums; no max-shift)
        float num0 = 0.f, den0 = 0.f, num1 = 0.f, den1 = 0.f;
#pragma unroll
        for (int lm = 0; lm < 2; ++lm)
#pragma unroll
            for (int r = 0; r < 4; ++r) {
                const float mlm = (lm == 1) ? (r < 2 ? mk01 : mk23) : 1.f;
                float t0 = pxv0 + acc[lm][1][0][r];
                float t1 = pxv1 + acc[lm][1][1][r];
                t0 = fmaxf(t0, 0.2f * t0);
                t1 = fmaxf(t1, 0.2f * t1);
                const float e0 = __expf(t0) * mlm;
                const float e1 = __expf(t1) * mlm;
                den0 += e0; num0 = fmaf(e0, acc[lm][0][0][r], num0);
                den1 += e1; num1 = fmaf(e1, acc[lm][0][1][r], num1);
            }
        den0 += __shfl_xor(den0, 16); den0 += __shfl_xor(den0, 32);
        num0 += __shfl_xor(num0, 16); num0 += __shfl_xor(num0, 32);
        den1 += __shfl_xor(den1, 16); den1 += __shfl_xor(den1, 32);
        num1 += __shfl_xor(num1, 16); num1 += __shfl_xor(num1, 32);

        const int ib = i & 1;
        if (h == 1 && g == 0) {
            exch[ib][q][0][c]      = num0;
            exch[ib][q][1][c]      = den0;
            exch[ib][q][0][16 + c] = num1;
            exch[ib][q][1][16 + c] = den1;
        }
        // order: exch writes visible before reads; NO vmcnt drain (A-prefetch
        // and out-stores stay in flight across the barrier)
        asm volatile("s_waitcnt lgkmcnt(0)" ::: "memory");
        __builtin_amdgcn_sched_barrier(0);
        __builtin_amdgcn_s_barrier();

        if (h == 0 && g == 0) {
            const float nT0 = num0 + exch[ib][q][0][c];
            const float dT0 = den0 + exch[ib][q][1][c];
            const float nT1 = num1 + exch[ib][q][0][16 + c];
            const float dT1 = den1 + exch[ib][q][1][16 + c];
            out[(size_t)b * DD + q * 32 + c]      = __fdividef(nT0, dT0);
            out[(size_t)b * DD + q * 32 + 16 + c] = __fdividef(nT1, dT1);
        }
    }
#undef LOADK
#undef PHASE
}

extern "C" void kernel_launch(void* const* d_in, const int* in_sizes, int n_in,
                              void* d_out, int out_size, void* d_ws, size_t ws_size,
                              hipStream_t stream) {
    const float* x   = (const float*)d_in[0];  // [B, D]
    const float* nbr = (const float*)d_in[1];  // [B, N, D]
    const float* W   = (const float*)d_in[2];  // [D, D]
    const float* A_w = (const float*)d_in[3];  // [2D, D]
    const float* A_b = (const float*)d_in[4];  // [D]
    float* out = (float*)d_out;                // [B, D]
    const int B = in_sizes[0] / DD;

    compute_WA<<<dim3(DD, 2), DD, 0, stream>>>(W, A_w);
    cvt_weights<<<2 * DD, DD, 0, stream>>>(W);
    pxa_pre<<<(B + 31) / 32, 128, 0, stream>>>(x, A_b, B);
    attn_mfma<<<(B + NITS - 1) / NITS, 512, 0, stream>>>(nbr, out, B);
}

// Round 14
// 221.965 us; speedup vs baseline: 2.5387x; 2.5387x over previous
//
#include <hip/hip_runtime.h>
#include <math.h>

#define NN 50          // neighbours
#define DD 128         // embedding dim
#define MT 4           // 4 m-tiles of 16 rows (50 padded to 64)
#define KT 4           // 4 k-tiles of 32 (K=128)
#define NIT 64         // b's per block  (grid = B/NIT = 512 = 2 blocks/CU)
#define TILE_H 12800   // 50 rows * 256 B (fp16 tile)

typedef __attribute__((ext_vector_type(4))) float  f32x4;
typedef __attribute__((ext_vector_type(2))) __fp16 f16x2;   // cvt_pkrtz return type
typedef __attribute__((ext_vector_type(4))) __fp16 f16x4;
typedef __attribute__((ext_vector_type(8))) __fp16 f16x8;

// fp32 scratch for W@A1 / W@A2, then fp16 transposed weight tables.
__device__ float g_WA1f[DD * DD];
__device__ float g_WA2f[DD * DD];
__device__ __attribute__((aligned(16))) __fp16 g_Wt[2 * DD * DD];  // [col 0..255][k]: [W | W@A2]^T
__device__ __attribute__((aligned(16))) __fp16 g_W1t[DD * DD];     // [col d][k]     : (W@A1)^T

__global__ void compute_WA(const float* __restrict__ W,
                           const float* __restrict__ A_w) {
    const int d = threadIdx.x, k = blockIdx.x, m = blockIdx.y;
    const float* __restrict__ A = A_w + (size_t)m * DD * DD;
    float acc = 0.f;
#pragma unroll 8
    for (int j = 0; j < DD; ++j)
        acc = fmaf(W[k * DD + j], A[j * DD + d], acc);
    if (m == 0) g_WA1f[k * DD + d] = acc;
    else        g_WA2f[k * DD + d] = acc;
}

__global__ void cvt_weights(const float* __restrict__ W) {
    const int n = blockIdx.x;      // 0..383
    const int k = threadIdx.x;     // 0..127
    if (n < DD)          g_Wt[n * DD + k]             = (__fp16)W[k * DD + n];
    else if (n < 2 * DD) g_Wt[n * DD + k]             = (__fp16)g_WA2f[k * DD + (n - DD)];
    else                 g_W1t[(n - 2 * DD) * DD + k] = (__fp16)g_WA1f[k * DD + (n - 2 * DD)];
}

// 8 consecutive fp32 -> 8 fp16 (packed RTZ converts, 4 instrs)
__device__ __forceinline__ f16x8 cvt8(float4 f0, float4 f1) {
    union { f16x2 h[4]; f16x8 v; } u;
    u.h[0] = __builtin_amdgcn_cvt_pkrtz(f0.x, f0.y);
    u.h[1] = __builtin_amdgcn_cvt_pkrtz(f0.z, f0.w);
    u.h[2] = __builtin_amdgcn_cvt_pkrtz(f1.x, f1.y);
    u.h[3] = __builtin_amdgcn_cvt_pkrtz(f1.z, f1.w);
    return u.v;
}

#define MFMA(a, b, c) __builtin_amdgcn_mfma_f32_16x16x32_f16((a), (b), (c), 0, 0, 0)

// v14 = r10 (best, 215 us) + three reg-safe latency cuts:
//  (1) softmax's shfl-chain + divide + store moved AFTER the barrier: the
//      ~4x30cy shuffle latency + div + store no longer inflate every wave's
//      barrier arrival (only num/den = 4 regs live across; acc dies at exp).
//  (2) swizzled ds_write addresses hoisted out of the loop (+4 VGPR, -25 VALU/it)
//  (3) s_setprio(1) around the MFMA cluster (2 blocks/CU at independent
//      phases = the attn-positive setprio regime, not lockstep-GEMM-null).
// r11/r12/r13 lessons: stay <=128 VGPR, no cross-block sharing, keep LDS
// staging as the transpose engine.
__global__ __launch_bounds__(512, 4)
void attn_mfma(const float* __restrict__ x,
               const float* __restrict__ nbr,
               const float* __restrict__ A_b,
               float* __restrict__ out, int B) {
    __shared__ __attribute__((aligned(16))) char tiles[2][TILE_H];  // 25.6 KB
    __shared__ float pxa_lds[NIT][DD];                              // 32.8 KB

    const int tid  = threadIdx.x;
    const int w    = tid >> 6;     // 0..7
    const int lane = tid & 63;
    const int c    = lane & 15;    // A-row / B-col / D-col lane index
    const int g    = lane >> 4;    // k-group / D-row group
    const size_t b0 = (size_t)blockIdx.x * NIT;
    const int col  = 16 * w + c;   // this wave's output column

    // ---- Phase A: pxa_lds[i][col] = A_b[col] + (x[b0+i] @ WA1)[col] ----
    {
        f32x4 pacc[MT];
#pragma unroll
        for (int mt = 0; mt < MT; ++mt) pacc[mt] = (f32x4)0.f;
#pragma unroll
        for (int mt = 0; mt < MT; ++mt) {
            long brow = (long)b0 + 16 * mt + c;
            if (brow > B - 1) brow = B - 1;
            const float4* __restrict__ xp =
                reinterpret_cast<const float4*>(x + brow * DD);
#pragma unroll
            for (int kt = 0; kt < KT; ++kt) {
                const f16x8 a = cvt8(xp[8 * kt + 2 * g], xp[8 * kt + 2 * g + 1]);
                const f16x8 bw = *reinterpret_cast<const f16x8*>(
                    g_W1t + col * DD + 32 * kt + 8 * g);
                pacc[mt] = MFMA(a, bw, pacc[mt]);
            }
        }
        const float ab = A_b[col];
#pragma unroll
        for (int mt = 0; mt < MT; ++mt)
#pragma unroll
            for (int r = 0; r < 4; ++r)
                pxa_lds[16 * mt + 4 * g + r][col] = pacc[mt][r] + ab;
    }

    // ---- B fragments (this wave's 16 cols, parts W and WA2), pinned ----
    f16x8 bF[2][KT];               // 32 VGPRs
#pragma unroll
    for (int p = 0; p < 2; ++p)
#pragma unroll
        for (int kt = 0; kt < KT; ++kt) {
            bF[p][kt] = *reinterpret_cast<const f16x8*>(
                g_Wt + (p * DD + col) * DD + 32 * kt + 8 * g);
            asm volatile("" : "+v"(bF[p][kt]));   // no remat/sink
        }

    // ---- staging registers: wave's share of one tile (<=4 chunks) ----
    float4 ra[4];                  // 16 VGPRs

    // hoisted swizzled ds_write byte-offsets (lane-dependent, loop-invariant)
    int wad[4];
#pragma unroll
    for (int j = 0; j < 4; ++j) {
        const int p  = w + 8 * j;
        const int lb = p * 512 + lane * 8;       // fp16-tile byte offset
        wad[j] = lb ^ (((lb >> 8) & 7) << 4);
    }

    auto load_tile = [&](int it) {
        int itc = it < NIT ? it : NIT - 1;        // tail: harmless re-load
        size_t bidx = b0 + (size_t)itc;
        if (bidx > (size_t)(B - 1)) bidx = (size_t)(B - 1);
        const float4* __restrict__ nb4 =
            reinterpret_cast<const float4*>(nbr + bidx * (size_t)(NN * DD));
#pragma unroll
        for (int j = 0; j < 4; ++j) {
            const int p = w + 8 * j;              // wave-uniform pass id
            if (p < 25) ra[j] = nb4[p * 64 + lane];
        }
    };

    auto write_tile = [&](char* dst) {
#pragma unroll
        for (int j = 0; j < 4; ++j) {
            if (w + 8 * j < 25) {
                union { f16x2 h[2]; f16x4 v; } u;
                u.h[0] = __builtin_amdgcn_cvt_pkrtz(ra[j].x, ra[j].y);
                u.h[1] = __builtin_amdgcn_cvt_pkrtz(ra[j].z, ra[j].w);
                *reinterpret_cast<f16x4*>(dst + wad[j]) = u.v;   // ds_write_b64
            }
        }
    };

    // ---- prologue: tile0 -> LDS, tile1 -> regs ----
    load_tile(0);
    write_tile(tiles[0]);          // compiler inserts exact vmcnt for ra
    load_tile(1);
    asm volatile("s_waitcnt lgkmcnt(0)" ::: "memory");
    __builtin_amdgcn_sched_barrier(0);
    __builtin_amdgcn_s_barrier();  // tiles[0] + pxa_lds visible to all waves

    const float m0v = (g == 0) ? 1.f : 0.f;  // rows 48,49 valid iff g==0 (mt=3,r<2)

#pragma unroll 1
    for (int i = 0; i < NIT; ++i) {
        // (a) regs (tile i+1) -> LDS buf[(i+1)&1]
        write_tile(tiles[(i + 1) & 1]);
        // (b) issue loads for tile i+2 (HBM latency hides under (c))
        load_tile(i + 2);
        __builtin_amdgcn_sched_barrier(0);   // pin load-issue ABOVE compute

        // (c) compute tile i
        const char* __restrict__ tile = tiles[i & 1];
        f32x4 acc[MT][2];
#pragma unroll
        for (int mt = 0; mt < MT; ++mt)
#pragma unroll
            for (int p = 0; p < 2; ++p) acc[mt][p] = (f32x4)0.f;

        __builtin_amdgcn_s_setprio(1);
#pragma unroll
        for (int mt = 0; mt < MT; ++mt) {
            int row = 16 * mt + c;
            if (row > NN - 1) row = NN - 1;  // pad rows masked in softmax
            const int rb = row * 256;
            const int sw = (row & 7) << 4;
#pragma unroll
            for (int kt = 0; kt < KT; ++kt) {
                const f16x8 a = *reinterpret_cast<const f16x8*>(
                    tile + ((rb + kt * 64 + g * 16) ^ sw));
                acc[mt][0] = MFMA(a, bF[0][kt], acc[mt][0]);
                acc[mt][1] = MFMA(a, bF[1][kt], acc[mt][1]);
            }
        }
        __builtin_amdgcn_s_setprio(0);

        // exp + per-lane partial sums (consumes acc) — BEFORE the barrier
        float den = 0.f, num = 0.f;
        {
            const float pxa = pxa_lds[i][col];
#pragma unroll
            for (int mt = 0; mt < MT; ++mt)
#pragma unroll
                for (int r = 0; r < 4; ++r) {
                    if (mt == 3 && r >= 2) continue;     // n >= 52: never valid
                    float t = pxa + acc[mt][1][r];
                    t = fmaxf(t, 0.2f * t);              // leaky_relu(0.2)
                    float p = __expf(t);
                    if (mt == 3) p *= m0v;               // n=48,49 valid iff g==0
                    den += p;
                    num = fmaf(p, acc[mt][0][r], num);
                }
        }

        // (d) all LDS ops done before any wave rewrites buffers next iter
        asm volatile("s_waitcnt lgkmcnt(0)" ::: "memory");
        __builtin_amdgcn_sched_barrier(0);
        __builtin_amdgcn_s_barrier();

        // cross-lane reduce + divide + store AFTER the barrier: off the
        // barrier-arrival path; only num/den (4 regs) carried across.
        den += __shfl_xor(den, 16); den += __shfl_xor(den, 32);
        num += __shfl_xor(num, 16); num += __shfl_xor(num, 32);
        if (g == 0 && b0 + i < (size_t)B)
            out[(b0 + i) * DD + col] = __fdividef(num, den);
    }
}

extern "C" void kernel_launch(void* const* d_in, const int* in_sizes, int n_in,
                              void* d_out, int out_size, void* d_ws, size_t ws_size,
                              hipStream_t stream) {
    const float* x   = (const float*)d_in[0];  // [B, D]
    const float* nbr = (const float*)d_in[1];  // [B, N, D]
    const float* W   = (const float*)d_in[2];  // [D, D]
    const float* A_w = (const float*)d_in[3];  // [2D, D]
    const float* A_b = (const float*)d_in[4];  // [D]
    float* out = (float*)d_out;                // [B, D]
    const int B = in_sizes[0] / DD;

    compute_WA<<<dim3(DD, 2), DD, 0, stream>>>(W, A_w);
    cvt_weights<<<3 * DD, DD, 0, stream>>>(W);
    const int grid = (B + NIT - 1) / NIT;      // 512 blocks = 2/CU, one round
    attn_mfma<<<grid, 512, 0, stream>>>(x, nbr, A_b, out, B);
}

// Round 15
// 213.762 us; speedup vs baseline: 2.6361x; 1.0384x over previous
//
#include <hip/hip_runtime.h>
#include <math.h>

#define NN 50          // neighbours
#define DD 128         // embedding dim
#define MT 4           // 4 m-tiles of 16 rows (50 padded to 64)
#define KT 4           // 4 k-tiles of 32 (K=128)
#define NIT 64         // b's per block  (grid = B/NIT = 512 = 2 blocks/CU)
#define TILE_H 12800   // 50 rows * 256 B (fp16 tile)

typedef __attribute__((ext_vector_type(4))) float  f32x4;
typedef __attribute__((ext_vector_type(2))) __fp16 f16x2;   // cvt_pkrtz return type
typedef __attribute__((ext_vector_type(4))) __fp16 f16x4;
typedef __attribute__((ext_vector_type(8))) __fp16 f16x8;

// fp32 scratch for W@A1 / W@A2, then fp16 transposed weight tables.
__device__ float g_WA1f[DD * DD];
__device__ float g_WA2f[DD * DD];
__device__ __attribute__((aligned(16))) __fp16 g_Wt[2 * DD * DD];  // [col 0..255][k]: [W | W@A2]^T
__device__ __attribute__((aligned(16))) __fp16 g_W1t[DD * DD];     // [col d][k]     : (W@A1)^T

__global__ void compute_WA(const float* __restrict__ W,
                           const float* __restrict__ A_w) {
    const int d = threadIdx.x, k = blockIdx.x, m = blockIdx.y;
    const float* __restrict__ A = A_w + (size_t)m * DD * DD;
    float acc = 0.f;
#pragma unroll 8
    for (int j = 0; j < DD; ++j)
        acc = fmaf(W[k * DD + j], A[j * DD + d], acc);
    if (m == 0) g_WA1f[k * DD + d] = acc;
    else        g_WA2f[k * DD + d] = acc;
}

__global__ void cvt_weights(const float* __restrict__ W) {
    const int n = blockIdx.x;      // 0..383
    const int k = threadIdx.x;     // 0..127
    if (n < DD)          g_Wt[n * DD + k]             = (__fp16)W[k * DD + n];
    else if (n < 2 * DD) g_Wt[n * DD + k]             = (__fp16)g_WA2f[k * DD + (n - DD)];
    else                 g_W1t[(n - 2 * DD) * DD + k] = (__fp16)g_WA1f[k * DD + (n - 2 * DD)];
}

// 8 consecutive fp32 -> 8 fp16 (packed RTZ converts, 4 instrs)
__device__ __forceinline__ f16x8 cvt8(float4 f0, float4 f1) {
    union { f16x2 h[4]; f16x8 v; } u;
    u.h[0] = __builtin_amdgcn_cvt_pkrtz(f0.x, f0.y);
    u.h[1] = __builtin_amdgcn_cvt_pkrtz(f0.z, f0.w);
    u.h[2] = __builtin_amdgcn_cvt_pkrtz(f1.x, f1.y);
    u.h[3] = __builtin_amdgcn_cvt_pkrtz(f1.z, f1.w);
    return u.v;
}

#define MFMA(a, b, c) __builtin_amdgcn_mfma_f32_16x16x32_f16((a), (b), (c), 0, 0, 0)

// v15 = r10 (best, 215 us) + NONTEMPORAL nbr loads, nothing else.
// r10-r14 budget (corrected): per iter 8064 cy/CU with HBM-share 62%, LDS 37%,
// VALU 13%, MFMA 8% -> nothing saturated, yet aggregate read rate = 4.07 TB/s.
// FETCH_SIZE shows only 418 of 875 MB from HBM: the Infinity-Cache-resident
// half (replay artifact; nbr has ZERO intra-kernel reuse) is served at ~2 TB/s
// and the request stream queues behind it. nt (no-allocate) pushes the whole
// stream to the HBM path that the harness's own fills prove does 6.7+ TB/s.
__global__ __launch_bounds__(512, 4)
void attn_mfma(const float* __restrict__ x,
               const float* __restrict__ nbr,
               const float* __restrict__ A_b,
               float* __restrict__ out, int B) {
    __shared__ __attribute__((aligned(16))) char tiles[2][TILE_H];  // 25.6 KB
    __shared__ float pxa_lds[NIT][DD];                              // 32.8 KB

    const int tid  = threadIdx.x;
    const int w    = tid >> 6;     // 0..7
    const int lane = tid & 63;
    const int c    = lane & 15;    // A-row / B-col / D-col lane index
    const int g    = lane >> 4;    // k-group / D-row group
    const size_t b0 = (size_t)blockIdx.x * NIT;
    const int col  = 16 * w + c;   // this wave's output column

    // ---- Phase A: pxa_lds[i][col] = A_b[col] + (x[b0+i] @ WA1)[col] ----
    {
        f32x4 pacc[MT];
#pragma unroll
        for (int mt = 0; mt < MT; ++mt) pacc[mt] = (f32x4)0.f;
#pragma unroll
        for (int mt = 0; mt < MT; ++mt) {
            long brow = (long)b0 + 16 * mt + c;
            if (brow > B - 1) brow = B - 1;
            const float4* __restrict__ xp =
                reinterpret_cast<const float4*>(x + brow * DD);
#pragma unroll
            for (int kt = 0; kt < KT; ++kt) {
                const f16x8 a = cvt8(xp[8 * kt + 2 * g], xp[8 * kt + 2 * g + 1]);
                const f16x8 bw = *reinterpret_cast<const f16x8*>(
                    g_W1t + col * DD + 32 * kt + 8 * g);
                pacc[mt] = MFMA(a, bw, pacc[mt]);
            }
        }
        const float ab = A_b[col];
#pragma unroll
        for (int mt = 0; mt < MT; ++mt)
#pragma unroll
            for (int r = 0; r < 4; ++r)
                pxa_lds[16 * mt + 4 * g + r][col] = pacc[mt][r] + ab;
    }

    // ---- B fragments (this wave's 16 cols, parts W and WA2), pinned ----
    f16x8 bF[2][KT];               // 32 VGPRs
#pragma unroll
    for (int p = 0; p < 2; ++p)
#pragma unroll
        for (int kt = 0; kt < KT; ++kt) {
            bF[p][kt] = *reinterpret_cast<const f16x8*>(
                g_Wt + (p * DD + col) * DD + 32 * kt + 8 * g);
            asm volatile("" : "+v"(bF[p][kt]));   // no remat/sink
        }

    // ---- staging registers: wave's share of one tile (<=4 chunks) ----
    f32x4 ra[4];                   // 16 VGPRs

    auto load_tile = [&](int it) {
        int itc = it < NIT ? it : NIT - 1;        // tail: harmless re-load
        size_t bidx = b0 + (size_t)itc;
        if (bidx > (size_t)(B - 1)) bidx = (size_t)(B - 1);
        const f32x4* __restrict__ nb4 =
            reinterpret_cast<const f32x4*>(nbr + bidx * (size_t)(NN * DD));
#pragma unroll
        for (int j = 0; j < 4; ++j) {
            const int p = w + 8 * j;              // wave-uniform pass id
            if (p < 25)                           // nt: no L3 allocation
                ra[j] = __builtin_nontemporal_load(nb4 + p * 64 + lane);
        }
    };

    // fp16 tile row = 256 B; byte addr XOR-swizzled by ((row&7)<<4).
    auto write_tile = [&](char* dst) {
#pragma unroll
        for (int j = 0; j < 4; ++j) {
            const int p = w + 8 * j;
            if (p < 25) {
                const int lb  = p * 512 + lane * 8;   // fp16-tile byte offset
                const int row = lb >> 8;
                const int ad  = lb ^ ((row & 7) << 4);
                union { f16x2 h[2]; f16x4 v; } u;
                u.h[0] = __builtin_amdgcn_cvt_pkrtz(ra[j][0], ra[j][1]);
                u.h[1] = __builtin_amdgcn_cvt_pkrtz(ra[j][2], ra[j][3]);
                *reinterpret_cast<f16x4*>(dst + ad) = u.v;   // ds_write_b64
            }
        }
    };

    // ---- prologue: tile0 -> LDS, tile1 -> regs ----
    load_tile(0);
    write_tile(tiles[0]);          // compiler inserts exact vmcnt for ra
    load_tile(1);
    asm volatile("s_waitcnt lgkmcnt(0)" ::: "memory");
    __builtin_amdgcn_sched_barrier(0);
    __builtin_amdgcn_s_barrier();  // tiles[0] + pxa_lds visible to all waves

    const float m0v = (g == 0) ? 1.f : 0.f;  // rows 48,49 valid iff g==0 (mt=3,r<2)

#pragma unroll 1
    for (int i = 0; i < NIT; ++i) {
        // (a) regs (tile i+1) -> LDS buf[(i+1)&1]
        write_tile(tiles[(i + 1) & 1]);
        // (b) issue loads for tile i+2 (HBM latency hides under (c))
        load_tile(i + 2);
        __builtin_amdgcn_sched_barrier(0);   // pin load-issue ABOVE compute

        // (c) compute tile i
        const char* __restrict__ tile = tiles[i & 1];
        f32x4 acc[MT][2];
#pragma unroll
        for (int mt = 0; mt < MT; ++mt)
#pragma unroll
            for (int p = 0; p < 2; ++p) acc[mt][p] = (f32x4)0.f;

#pragma unroll
        for (int mt = 0; mt < MT; ++mt) {
            int row = 16 * mt + c;
            if (row > NN - 1) row = NN - 1;  // pad rows masked in softmax
            const int rb = row * 256;
            const int sw = (row & 7) << 4;
#pragma unroll
            for (int kt = 0; kt < KT; ++kt) {
                const f16x8 a = *reinterpret_cast<const f16x8*>(
                    tile + ((rb + kt * 64 + g * 16) ^ sw));
                acc[mt][0] = MFMA(a, bF[0][kt], acc[mt][0]);
                acc[mt][1] = MFMA(a, bF[1][kt], acc[mt][1]);
            }
        }

        // softmax over n for this wave's col (no max-shift: logits ~N(0,1.4))
        {
            const float pxa = pxa_lds[i][col];
            float den = 0.f, num = 0.f;
#pragma unroll
            for (int mt = 0; mt < MT; ++mt)
#pragma unroll
                for (int r = 0; r < 4; ++r) {
                    if (mt == 3 && r >= 2) continue;     // n >= 52: never valid
                    float t = pxa + acc[mt][1][r];
                    t = fmaxf(t, 0.2f * t);              // leaky_relu(0.2)
                    float p = __expf(t);
                    if (mt == 3) p *= m0v;               // n=48,49 valid iff g==0
                    den += p;
                    num = fmaf(p, acc[mt][0][r], num);
                }
            den += __shfl_xor(den, 16); den += __shfl_xor(den, 32);
            num += __shfl_xor(num, 16); num += __shfl_xor(num, 32);
            if (g == 0 && b0 + i < (size_t)B)
                out[(b0 + i) * DD + col] = __fdividef(num, den);
        }

        // (d) all LDS ops done before any wave rewrites buffers next iter
        asm volatile("s_waitcnt lgkmcnt(0)" ::: "memory");
        __builtin_amdgcn_sched_barrier(0);
        __builtin_amdgcn_s_barrier();
    }
}

extern "C" void kernel_launch(void* const* d_in, const int* in_sizes, int n_in,
                              void* d_out, int out_size, void* d_ws, size_t ws_size,
                              hipStream_t stream) {
    const float* x   = (const float*)d_in[0];  // [B, D]
    const float* nbr = (const float*)d_in[1];  // [B, N, D]
    const float* W   = (const float*)d_in[2];  // [D, D]
    const float* A_w = (const float*)d_in[3];  // [2D, D]
    const float* A_b = (const float*)d_in[4];  // [D]
    float* out = (float*)d_out;                // [B, D]
    const int B = in_sizes[0] / DD;

    compute_WA<<<dim3(DD, 2), DD, 0, stream>>>(W, A_w);
    cvt_weights<<<3 * DD, DD, 0, stream>>>(W);
    const int grid = (B + NIT - 1) / NIT;      // 512 blocks = 2/CU, one round
    attn_mfma<<<grid, 512, 0, stream>>>(x, nbr, A_b, out, B);
}

// Round 16
// 212.016 us; speedup vs baseline: 2.6578x; 1.0082x over previous
//
#include <hip/hip_runtime.h>
#include <math.h>

#define NN 50          // neighbours
#define DD 128         // embedding dim
#define MT 4           // 4 m-tiles of 16 rows (50 padded to 64)
#define KT 4           // 4 k-tiles of 32 (K=128)
#define NIT 64         // b's per block  (grid = B/NIT = 512 = 2 blocks/CU)
#define TILE_H 12800   // 50 rows * 256 B (fp16 tile)

typedef __attribute__((ext_vector_type(4))) float  f32x4;
typedef __attribute__((ext_vector_type(2))) __fp16 f16x2;   // cvt_pkrtz return type
typedef __attribute__((ext_vector_type(4))) __fp16 f16x4;
typedef __attribute__((ext_vector_type(8))) __fp16 f16x8;

// fp32 scratch for W@A1 / W@A2, then fp16 transposed weight tables.
__device__ float g_WA1f[DD * DD];
__device__ float g_WA2f[DD * DD];
__device__ __attribute__((aligned(16))) __fp16 g_Wt[2 * DD * DD];  // [col 0..255][k]: [W | W@A2]^T
__device__ __attribute__((aligned(16))) __fp16 g_W1t[DD * DD];     // [col d][k]     : (W@A1)^T

__global__ void compute_WA(const float* __restrict__ W,
                           const float* __restrict__ A_w) {
    const int d = threadIdx.x, k = blockIdx.x, m = blockIdx.y;
    const float* __restrict__ A = A_w + (size_t)m * DD * DD;
    float acc = 0.f;
#pragma unroll 8
    for (int j = 0; j < DD; ++j)
        acc = fmaf(W[k * DD + j], A[j * DD + d], acc);
    if (m == 0) g_WA1f[k * DD + d] = acc;
    else        g_WA2f[k * DD + d] = acc;
}

__global__ void cvt_weights(const float* __restrict__ W) {
    const int n = blockIdx.x;      // 0..383
    const int k = threadIdx.x;     // 0..127
    if (n < DD)          g_Wt[n * DD + k]             = (__fp16)W[k * DD + n];
    else if (n < 2 * DD) g_Wt[n * DD + k]             = (__fp16)g_WA2f[k * DD + (n - DD)];
    else                 g_W1t[(n - 2 * DD) * DD + k] = (__fp16)g_WA1f[k * DD + (n - 2 * DD)];
}

// 8 consecutive fp32 -> 8 fp16 (packed RTZ converts, 4 instrs)
__device__ __forceinline__ f16x8 cvt8(float4 f0, float4 f1) {
    union { f16x2 h[4]; f16x8 v; } u;
    u.h[0] = __builtin_amdgcn_cvt_pkrtz(f0.x, f0.y);
    u.h[1] = __builtin_amdgcn_cvt_pkrtz(f0.z, f0.w);
    u.h[2] = __builtin_amdgcn_cvt_pkrtz(f1.x, f1.y);
    u.h[3] = __builtin_amdgcn_cvt_pkrtz(f1.z, f1.w);
    return u.v;
}

#define MFMA(a, b, c) __builtin_amdgcn_mfma_f32_16x16x32_f16((a), (b), (c), 0, 0, 0)

// v16 = r15 + SPLIT LOAD ISSUE. Steady-state audit: all 16 waves/CU issue
// their 4 tile-loads in one barrier-aligned burst (64 KB in flight), HBM
// drains it in ~6400 cy of the 8030 cy period -> VMEM queue empty ~1600 cy
// per period, and the block barrier re-aligns every wave to the same burst
// phase so the gap never heals. Fix: issue ra[0..1] at iteration top,
// ra[2..3] between the two compute halves — same regs, same barriers, pure
// issue smoothing to keep the queue non-empty.
__global__ __launch_bounds__(512, 4)
void attn_mfma(const float* __restrict__ x,
               const float* __restrict__ nbr,
               const float* __restrict__ A_b,
               float* __restrict__ out, int B) {
    __shared__ __attribute__((aligned(16))) char tiles[2][TILE_H];  // 25.6 KB
    __shared__ float pxa_lds[NIT][DD];                              // 32.8 KB

    const int tid  = threadIdx.x;
    const int w    = tid >> 6;     // 0..7
    const int lane = tid & 63;
    const int c    = lane & 15;    // A-row / B-col / D-col lane index
    const int g    = lane >> 4;    // k-group / D-row group
    const size_t b0 = (size_t)blockIdx.x * NIT;
    const int col  = 16 * w + c;   // this wave's output column

    // ---- Phase A: pxa_lds[i][col] = A_b[col] + (x[b0+i] @ WA1)[col] ----
    {
        f32x4 pacc[MT];
#pragma unroll
        for (int mt = 0; mt < MT; ++mt) pacc[mt] = (f32x4)0.f;
#pragma unroll
        for (int mt = 0; mt < MT; ++mt) {
            long brow = (long)b0 + 16 * mt + c;
            if (brow > B - 1) brow = B - 1;
            const float4* __restrict__ xp =
                reinterpret_cast<const float4*>(x + brow * DD);
#pragma unroll
            for (int kt = 0; kt < KT; ++kt) {
                const f16x8 a = cvt8(xp[8 * kt + 2 * g], xp[8 * kt + 2 * g + 1]);
                const f16x8 bw = *reinterpret_cast<const f16x8*>(
                    g_W1t + col * DD + 32 * kt + 8 * g);
                pacc[mt] = MFMA(a, bw, pacc[mt]);
            }
        }
        const float ab = A_b[col];
#pragma unroll
        for (int mt = 0; mt < MT; ++mt)
#pragma unroll
            for (int r = 0; r < 4; ++r)
                pxa_lds[16 * mt + 4 * g + r][col] = pacc[mt][r] + ab;
    }

    // ---- B fragments (this wave's 16 cols, parts W and WA2), pinned ----
    f16x8 bF[2][KT];               // 32 VGPRs
#pragma unroll
    for (int p = 0; p < 2; ++p)
#pragma unroll
        for (int kt = 0; kt < KT; ++kt) {
            bF[p][kt] = *reinterpret_cast<const f16x8*>(
                g_Wt + (p * DD + col) * DD + 32 * kt + 8 * g);
            asm volatile("" : "+v"(bF[p][kt]));   // no remat/sink
        }

    // ---- staging registers: wave's share of one tile (<=4 chunks) ----
    f32x4 ra[4];                   // 16 VGPRs

    auto nb4_of = [&](int it) {
        int itc = it < NIT ? it : NIT - 1;        // tail: harmless re-load
        size_t bidx = b0 + (size_t)itc;
        if (bidx > (size_t)(B - 1)) bidx = (size_t)(B - 1);
        return reinterpret_cast<const f32x4*>(nbr + bidx * (size_t)(NN * DD));
    };
    // half 0: chunks w, w+8 ; half 1: chunks w+16, w+24
    auto load_half = [&](int it, int hf) {
        const f32x4* __restrict__ nb4 = nb4_of(it);
#pragma unroll
        for (int j = 2 * hf; j < 2 * hf + 2; ++j) {
            const int p = w + 8 * j;
            if (p < 25)                           // nt: no L3 allocation
                ra[j] = __builtin_nontemporal_load(nb4 + p * 64 + lane);
        }
    };

    // fp16 tile row = 256 B; byte addr XOR-swizzled by ((row&7)<<4).
    auto write_tile = [&](char* dst) {
#pragma unroll
        for (int j = 0; j < 4; ++j) {
            const int p = w + 8 * j;
            if (p < 25) {
                const int lb  = p * 512 + lane * 8;   // fp16-tile byte offset
                const int row = lb >> 8;
                const int ad  = lb ^ ((row & 7) << 4);
                union { f16x2 h[2]; f16x4 v; } u;
                u.h[0] = __builtin_amdgcn_cvt_pkrtz(ra[j][0], ra[j][1]);
                u.h[1] = __builtin_amdgcn_cvt_pkrtz(ra[j][2], ra[j][3]);
                *reinterpret_cast<f16x4*>(dst + ad) = u.v;   // ds_write_b64
            }
        }
    };

    // one compute half: m-tiles mt0..mt0+1 accumulated into acc
    auto compute_half = [&](const char* tile, f32x4 (&acc)[MT][2], int mt0) {
#pragma unroll
        for (int mt = mt0; mt < mt0 + 2; ++mt) {
            int row = 16 * mt + c;
            if (row > NN - 1) row = NN - 1;  // pad rows masked in softmax
            const int rb = row * 256;
            const int sw = (row & 7) << 4;
#pragma unroll
            for (int kt = 0; kt < KT; ++kt) {
                const f16x8 a = *reinterpret_cast<const f16x8*>(
                    tile + ((rb + kt * 64 + g * 16) ^ sw));
                acc[mt][0] = MFMA(a, bF[0][kt], acc[mt][0]);
                acc[mt][1] = MFMA(a, bF[1][kt], acc[mt][1]);
            }
        }
    };

    // ---- prologue: tile0 -> LDS, tile1 -> regs ----
    load_half(0, 0); load_half(0, 1);
    write_tile(tiles[0]);          // compiler inserts exact vmcnt for ra
    load_half(1, 0); load_half(1, 1);
    asm volatile("s_waitcnt lgkmcnt(0)" ::: "memory");
    __builtin_amdgcn_sched_barrier(0);
    __builtin_amdgcn_s_barrier();  // tiles[0] + pxa_lds visible to all waves

    const float m0v = (g == 0) ? 1.f : 0.f;  // rows 48,49 valid iff g==0 (mt=3,r<2)

#pragma unroll 1
    for (int i = 0; i < NIT; ++i) {
        // (a) regs (tile i+1) -> LDS buf[(i+1)&1]
        write_tile(tiles[(i + 1) & 1]);
        // (b1) first half of tile i+2's loads
        load_half(i + 2, 0);
        __builtin_amdgcn_sched_barrier(0);   // pin issue ABOVE compute half 1

        const char* __restrict__ tile = tiles[i & 1];
        f32x4 acc[MT][2];
#pragma unroll
        for (int mt = 0; mt < MT; ++mt)
#pragma unroll
            for (int p = 0; p < 2; ++p) acc[mt][p] = (f32x4)0.f;

        // (c1) compute half 1 (mt 0,1)
        compute_half(tile, acc, 0);

        // (b2) second half of tile i+2's loads — mid-iteration issue point
        load_half(i + 2, 1);
        __builtin_amdgcn_sched_barrier(0);   // pin issue ABOVE compute half 2

        // (c2) compute half 2 (mt 2,3)
        compute_half(tile, acc, 2);

        // softmax over n for this wave's col (no max-shift: logits ~N(0,1.4))
        {
            const float pxa = pxa_lds[i][col];
            float den = 0.f, num = 0.f;
#pragma unroll
            for (int mt = 0; mt < MT; ++mt)
#pragma unroll
                for (int r = 0; r < 4; ++r) {
                    if (mt == 3 && r >= 2) continue;     // n >= 52: never valid
                    float t = pxa + acc[mt][1][r];
                    t = fmaxf(t, 0.2f * t);              // leaky_relu(0.2)
                    float p = __expf(t);
                    if (mt == 3) p *= m0v;               // n=48,49 valid iff g==0
                    den += p;
                    num = fmaf(p, acc[mt][0][r], num);
                }
            den += __shfl_xor(den, 16); den += __shfl_xor(den, 32);
            num += __shfl_xor(num, 16); num += __shfl_xor(num, 32);
            if (g == 0 && b0 + i < (size_t)B)
                out[(b0 + i) * DD + col] = __fdividef(num, den);
        }

        // (d) all LDS ops done before any wave rewrites buffers next iter
        asm volatile("s_waitcnt lgkmcnt(0)" ::: "memory");
        __builtin_amdgcn_sched_barrier(0);
        __builtin_amdgcn_s_barrier();
    }
}

extern "C" void kernel_launch(void* const* d_in, const int* in_sizes, int n_in,
                              void* d_out, int out_size, void* d_ws, size_t ws_size,
                              hipStream_t stream) {
    const float* x   = (const float*)d_in[0];  // [B, D]
    const float* nbr = (const float*)d_in[1];  // [B, N, D]
    const float* W   = (const float*)d_in[2];  // [D, D]
    const float* A_w = (const float*)d_in[3];  // [2D, D]
    const float* A_b = (const float*)d_in[4];  // [D]
    float* out = (float*)d_out;                // [B, D]
    const int B = in_sizes[0] / DD;

    compute_WA<<<dim3(DD, 2), DD, 0, stream>>>(W, A_w);
    cvt_weights<<<3 * DD, DD, 0, stream>>>(W);
    const int grid = (B + NIT - 1) / NIT;      // 512 blocks = 2/CU, one round
    attn_mfma<<<grid, 512, 0, stream>>>(x, nbr, A_b, out, B);
}

// Round 17
// 209.151 us; speedup vs baseline: 2.6942x; 1.0137x over previous
//
#include <hip/hip_runtime.h>
#include <math.h>

#define NN 50          // neighbours
#define DD 128         // embedding dim
#define MT 4           // 4 m-tiles of 16 rows (50 padded to 64)
#define KT 4           // 4 k-tiles of 32 (K=128)
#define NIT 64         // b's per block  (grid = B/NIT = 512 = 2 blocks/CU)
#define TILE_H 12800   // 50 rows * 256 B (fp16 tile)

typedef __attribute__((ext_vector_type(4))) float  f32x4;
typedef __attribute__((ext_vector_type(2))) __fp16 f16x2;   // cvt_pkrtz return type
typedef __attribute__((ext_vector_type(4))) __fp16 f16x4;
typedef __attribute__((ext_vector_type(8))) __fp16 f16x8;

// fp32 scratch for W@A1 / W@A2, then fp16 transposed weight tables.
__device__ float g_WA1f[DD * DD];
__device__ float g_WA2f[DD * DD];
__device__ __attribute__((aligned(16))) __fp16 g_Wt[2 * DD * DD];  // [col 0..255][k]: [W | W@A2]^T
__device__ __attribute__((aligned(16))) __fp16 g_W1t[DD * DD];     // [col d][k]     : (W@A1)^T

__global__ void compute_WA(const float* __restrict__ W,
                           const float* __restrict__ A_w) {
    const int d = threadIdx.x, k = blockIdx.x, m = blockIdx.y;
    const float* __restrict__ A = A_w + (size_t)m * DD * DD;
    float acc = 0.f;
#pragma unroll 8
    for (int j = 0; j < DD; ++j)
        acc = fmaf(W[k * DD + j], A[j * DD + d], acc);
    if (m == 0) g_WA1f[k * DD + d] = acc;
    else        g_WA2f[k * DD + d] = acc;
}

__global__ void cvt_weights(const float* __restrict__ W) {
    const int n = blockIdx.x;      // 0..383
    const int k = threadIdx.x;     // 0..127
    if (n < DD)          g_Wt[n * DD + k]             = (__fp16)W[k * DD + n];
    else if (n < 2 * DD) g_Wt[n * DD + k]             = (__fp16)g_WA2f[k * DD + (n - DD)];
    else                 g_W1t[(n - 2 * DD) * DD + k] = (__fp16)g_WA1f[k * DD + (n - 2 * DD)];
}

// 8 consecutive fp32 -> 8 fp16 (packed RTZ converts, 4 instrs)
__device__ __forceinline__ f16x8 cvt8(float4 f0, float4 f1) {
    union { f16x2 h[4]; f16x8 v; } u;
    u.h[0] = __builtin_amdgcn_cvt_pkrtz(f0.x, f0.y);
    u.h[1] = __builtin_amdgcn_cvt_pkrtz(f0.z, f0.w);
    u.h[2] = __builtin_amdgcn_cvt_pkrtz(f1.x, f1.y);
    u.h[3] = __builtin_amdgcn_cvt_pkrtz(f1.z, f1.w);
    return u.v;
}

#define MFMA(a, b, c) __builtin_amdgcn_mfma_f32_16x16x32_f16((a), (b), (c), 0, 0, 0)

// v17 = r16 + DEFERRED STORE. Diagnosis of the stable 212-222 us plateau:
// period (8064 cy) = HBM share (5018) + LDS share (~3000) -- the phases SUM
// instead of overlapping. Coupling: global_store shares the vmcnt counter
// with loads and only decrements on COMMIT (~900 cy at HBM). Every iter ends
// with 2 out-stores ~150 cy before the barrier; next iter's write_tile needs
// a compiler-inserted vmcnt wait for ra, which (conservative vmcnt(0)) also
// waits for those store commits -> ~700-900 cy stall gating the LDS phase,
// every wave, every iter, in ALL reg-staged versions r9-r16. Fix: carry
// num/den in 2 regs; store tile i's result at the TOP of iter i+1 (ancient
// by the next vmcnt-gated point). Epilogue stores the last tile.
__global__ __launch_bounds__(512, 4)
void attn_mfma(const float* __restrict__ x,
               const float* __restrict__ nbr,
               const float* __restrict__ A_b,
               float* __restrict__ out, int B) {
    __shared__ __attribute__((aligned(16))) char tiles[2][TILE_H];  // 25.6 KB
    __shared__ float pxa_lds[NIT][DD];                              // 32.8 KB

    const int tid  = threadIdx.x;
    const int w    = tid >> 6;     // 0..7
    const int lane = tid & 63;
    const int c    = lane & 15;    // A-row / B-col / D-col lane index
    const int g    = lane >> 4;    // k-group / D-row group
    const size_t b0 = (size_t)blockIdx.x * NIT;
    const int col  = 16 * w + c;   // this wave's output column

    // ---- Phase A: pxa_lds[i][col] = A_b[col] + (x[b0+i] @ WA1)[col] ----
    {
        f32x4 pacc[MT];
#pragma unroll
        for (int mt = 0; mt < MT; ++mt) pacc[mt] = (f32x4)0.f;
#pragma unroll
        for (int mt = 0; mt < MT; ++mt) {
            long brow = (long)b0 + 16 * mt + c;
            if (brow > B - 1) brow = B - 1;
            const float4* __restrict__ xp =
                reinterpret_cast<const float4*>(x + brow * DD);
#pragma unroll
            for (int kt = 0; kt < KT; ++kt) {
                const f16x8 a = cvt8(xp[8 * kt + 2 * g], xp[8 * kt + 2 * g + 1]);
                const f16x8 bw = *reinterpret_cast<const f16x8*>(
                    g_W1t + col * DD + 32 * kt + 8 * g);
                pacc[mt] = MFMA(a, bw, pacc[mt]);
            }
        }
        const float ab = A_b[col];
#pragma unroll
        for (int mt = 0; mt < MT; ++mt)
#pragma unroll
            for (int r = 0; r < 4; ++r)
                pxa_lds[16 * mt + 4 * g + r][col] = pacc[mt][r] + ab;
    }

    // ---- B fragments (this wave's 16 cols, parts W and WA2), pinned ----
    f16x8 bF[2][KT];               // 32 VGPRs
#pragma unroll
    for (int p = 0; p < 2; ++p)
#pragma unroll
        for (int kt = 0; kt < KT; ++kt) {
            bF[p][kt] = *reinterpret_cast<const f16x8*>(
                g_Wt + (p * DD + col) * DD + 32 * kt + 8 * g);
            asm volatile("" : "+v"(bF[p][kt]));   // no remat/sink
        }

    // ---- staging registers: wave's share of one tile (<=4 chunks) ----
    f32x4 ra[4];                   // 16 VGPRs

    auto nb4_of = [&](int it) {
        int itc = it < NIT ? it : NIT - 1;        // tail: harmless re-load
        size_t bidx = b0 + (size_t)itc;
        if (bidx > (size_t)(B - 1)) bidx = (size_t)(B - 1);
        return reinterpret_cast<const f32x4*>(nbr + bidx * (size_t)(NN * DD));
    };
    // half 0: chunks w, w+8 ; half 1: chunks w+16, w+24
    auto load_half = [&](int it, int hf) {
        const f32x4* __restrict__ nb4 = nb4_of(it);
#pragma unroll
        for (int j = 2 * hf; j < 2 * hf + 2; ++j) {
            const int p = w + 8 * j;
            if (p < 25)                           // nt: no L3 allocation
                ra[j] = __builtin_nontemporal_load(nb4 + p * 64 + lane);
        }
    };

    // fp16 tile row = 256 B; byte addr XOR-swizzled by ((row&7)<<4).
    auto write_tile = [&](char* dst) {
#pragma unroll
        for (int j = 0; j < 4; ++j) {
            const int p = w + 8 * j;
            if (p < 25) {
                const int lb  = p * 512 + lane * 8;   // fp16-tile byte offset
                const int row = lb >> 8;
                const int ad  = lb ^ ((row & 7) << 4);
                union { f16x2 h[2]; f16x4 v; } u;
                u.h[0] = __builtin_amdgcn_cvt_pkrtz(ra[j][0], ra[j][1]);
                u.h[1] = __builtin_amdgcn_cvt_pkrtz(ra[j][2], ra[j][3]);
                *reinterpret_cast<f16x4*>(dst + ad) = u.v;   // ds_write_b64
            }
        }
    };

    // one compute half: m-tiles mt0..mt0+1 accumulated into acc
    auto compute_half = [&](const char* tile, f32x4 (&acc)[MT][2], int mt0) {
#pragma unroll
        for (int mt = mt0; mt < mt0 + 2; ++mt) {
            int row = 16 * mt + c;
            if (row > NN - 1) row = NN - 1;  // pad rows masked in softmax
            const int rb = row * 256;
            const int sw = (row & 7) << 4;
#pragma unroll
            for (int kt = 0; kt < KT; ++kt) {
                const f16x8 a = *reinterpret_cast<const f16x8*>(
                    tile + ((rb + kt * 64 + g * 16) ^ sw));
                acc[mt][0] = MFMA(a, bF[0][kt], acc[mt][0]);
                acc[mt][1] = MFMA(a, bF[1][kt], acc[mt][1]);
            }
        }
    };

    // ---- prologue: tile0 -> LDS, tile1 -> regs ----
    load_half(0, 0); load_half(0, 1);
    write_tile(tiles[0]);          // compiler inserts exact vmcnt for ra
    load_half(1, 0); load_half(1, 1);
    asm volatile("s_waitcnt lgkmcnt(0)" ::: "memory");
    __builtin_amdgcn_sched_barrier(0);
    __builtin_amdgcn_s_barrier();  // tiles[0] + pxa_lds visible to all waves

    const float m0v = (g == 0) ? 1.f : 0.f;  // rows 48,49 valid iff g==0 (mt=3,r<2)

    float sNum = 0.f, sDen = 1.f;  // deferred-store carry (tile i-1's result)

#pragma unroll 1
    for (int i = 0; i < NIT; ++i) {
        // (a) regs (tile i+1) -> LDS buf[(i+1)&1]
        write_tile(tiles[(i + 1) & 1]);

        // (a') DEFERRED STORE of tile i-1's result: issued here, ~one full
        // iteration before the next vmcnt-gated point -> commit never stalls.
        if (i > 0 && g == 0)
            __builtin_nontemporal_store(__fdividef(sNum, sDen),
                                        out + (b0 + i - 1) * DD + col);

        // (b1) first half of tile i+2's loads
        load_half(i + 2, 0);
        __builtin_amdgcn_sched_barrier(0);   // pin issue ABOVE compute half 1

        const char* __restrict__ tile = tiles[i & 1];
        f32x4 acc[MT][2];
#pragma unroll
        for (int mt = 0; mt < MT; ++mt)
#pragma unroll
            for (int p = 0; p < 2; ++p) acc[mt][p] = (f32x4)0.f;

        // (c1) compute half 1 (mt 0,1)
        compute_half(tile, acc, 0);

        // (b2) second half of tile i+2's loads — mid-iteration issue point
        load_half(i + 2, 1);
        __builtin_amdgcn_sched_barrier(0);   // pin issue ABOVE compute half 2

        // (c2) compute half 2 (mt 2,3)
        compute_half(tile, acc, 2);

        // softmax over n for this wave's col (no max-shift: logits ~N(0,1.4))
        {
            const float pxa = pxa_lds[i][col];
            float den = 0.f, num = 0.f;
#pragma unroll
            for (int mt = 0; mt < MT; ++mt)
#pragma unroll
                for (int r = 0; r < 4; ++r) {
                    if (mt == 3 && r >= 2) continue;     // n >= 52: never valid
                    float t = pxa + acc[mt][1][r];
                    t = fmaxf(t, 0.2f * t);              // leaky_relu(0.2)
                    float p = __expf(t);
                    if (mt == 3) p *= m0v;               // n=48,49 valid iff g==0
                    den += p;
                    num = fmaf(p, acc[mt][0][r], num);
                }
            den += __shfl_xor(den, 16); den += __shfl_xor(den, 32);
            num += __shfl_xor(num, 16); num += __shfl_xor(num, 32);
            sNum = num; sDen = den;          // carry; stored next iteration
        }

        // (d) all LDS ops done before any wave rewrites buffers next iter
        asm volatile("s_waitcnt lgkmcnt(0)" ::: "memory");
        __builtin_amdgcn_sched_barrier(0);
        __builtin_amdgcn_s_barrier();
    }

    // epilogue: store the last tile's result
    if (g == 0)
        __builtin_nontemporal_store(__fdividef(sNum, sDen),
                                    out + (b0 + NIT - 1) * DD + col);
}

extern "C" void kernel_launch(void* const* d_in, const int* in_sizes, int n_in,
                              void* d_out, int out_size, void* d_ws, size_t ws_size,
                              hipStream_t stream) {
    const float* x   = (const float*)d_in[0];  // [B, D]
    const float* nbr = (const float*)d_in[1];  // [B, N, D]
    const float* W   = (const float*)d_in[2];  // [D, D]
    const float* A_w = (const float*)d_in[3];  // [2D, D]
    const float* A_b = (const float*)d_in[4];  // [D]
    float* out = (float*)d_out;                // [B, D]
    const int B = in_sizes[0] / DD;

    compute_WA<<<dim3(DD, 2), DD, 0, stream>>>(W, A_w);
    cvt_weights<<<3 * DD, DD, 0, stream>>>(W);
    const int grid = (B + NIT - 1) / NIT;      // 512 blocks = 2/CU, one round
    attn_mfma<<<grid, 512, 0, stream>>>(x, nbr, A_b, out, B);
}